// Round 2
// baseline (70.584 us; speedup 1.0000x reference)
//
#include <hip/hip_runtime.h>
#include <stdint.h>

// CandidateFinder: binary-quantize (x>0), exact match on two 32-bit dim
// groups (union), gather first <=64 matching key indices per query, pad -1.
//
// wave=64 lanes <-> 64 dims: __ballot(x>0) packs one row's sign bits into
// exactly the two uint32 group signatures. Match = equality on either group.
// Matches are emitted in ascending key order via ballot+popcount prefix,
// reproducing the reference's sort-then-truncate semantics exactly.
//
// R1 -> R2: removed the data-dependent `break` in the scan loop (match
// probability ~2^-31: the break never fires but serializes every iteration
// on a full L2-hit latency, ~32x250cyc/wave). Loads are now independent ->
// compiler pipelines them (vmcnt(N)). Query signatures precomputed in the
// sig kernel so the match kernel reads 8B/wave (scalar load) not 256B.

#define LSEQ 2048
#define DDIM 64
#define KMAX 64

// Kernel 1: one wave per row -> pack 64 sign bits into uint2 signature.
// Rows [0, nrows) = keys, rows [nrows, 2*nrows) = queries.
__global__ __launch_bounds__(256) void sig_kernel(
    const float* __restrict__ query, const float* __restrict__ key,
    uint2* __restrict__ ksig, uint2* __restrict__ qsig, int nrows) {
    int row  = (int)((blockIdx.x * blockDim.x + threadIdx.x) >> 6);  // wave id
    int lane = threadIdx.x & 63;
    if (row >= 2 * nrows) return;                   // wave-uniform
    bool is_key = row < nrows;
    int r = is_key ? row : row - nrows;
    const float* src = is_key ? key : query;
    float v = src[(size_t)r * DDIM + lane];         // coalesced 256B/wave
    unsigned long long m = __ballot(v > 0.0f);      // bit i = lane i sign
    if (lane == 0) {
        uint2 s = make_uint2((unsigned)m, (unsigned)(m >> 32));
        if (is_key) ksig[r] = s; else qsig[r] = s;
    }
}

// Kernel 2: one wave per query; scan the batch's 2048 key signatures in 32
// chunks of 64 (one key/lane, coalesced 512B/wave, L2-hot). No early exit:
// loads are independent -> pipelined. Match positions beyond KMAX are
// dropped; padding uses the total match count.
__global__ __launch_bounds__(256) void match_kernel(
    const uint2* __restrict__ qsig, const uint2* __restrict__ ksig,
    int* __restrict__ out, int nq) {
    int qid  = (int)((blockIdx.x * blockDim.x + threadIdx.x) >> 6);  // wave id
    int lane = threadIdx.x & 63;
    if (qid >= nq) return;                          // wave-uniform
    int b = qid >> 11;                              // qid / LSEQ

    uint2 qs = qsig[qid];                           // wave-uniform -> s_load
    unsigned q1 = qs.x, q2 = qs.y;

    const uint2* ks = ksig + (size_t)b * LSEQ;
    int* obase = out + (size_t)qid * KMAX;
    unsigned long long below = (1ull << lane) - 1ull;  // lanes strictly below

    int cnt = 0;
#pragma unroll 8
    for (int c = 0; c < LSEQ / 64; ++c) {
        uint2 kv = ks[c * 64 + lane];
        bool m = (kv.x == q1) || (kv.y == q2);
        unsigned long long mask = __ballot(m);
        if (m) {                                    // ~never taken
            int pos = cnt + __popcll(mask & below);
            if (pos < KMAX) obase[pos] = c * 64 + lane;
        }
        cnt += __popcll(mask);                      // wave-uniform scalar
    }
    // pad remaining slots with -1 (KMAX == 64 == lanes; disjoint from matches)
    if (lane >= cnt) obase[lane] = -1;
}

// Fallback if ws_size < 2*B*L*8 bytes: fused kernel, key sigs staged in LDS.
__global__ __launch_bounds__(256) void fused_kernel(
    const float* __restrict__ query, const float* __restrict__ key,
    int* __restrict__ out) {
    __shared__ uint2 ksig[LSEQ];                    // 16 KB
    const int blocksPerBatch = LSEQ / 64;           // 32
    int b    = blockIdx.x / blocksPerBatch;
    int qblk = blockIdx.x % blocksPerBatch;
    int lane = threadIdx.x & 63;
    int wave = threadIdx.x >> 6;

    const float* kb = key + (size_t)b * LSEQ * DDIM;
    for (int row = wave; row < LSEQ; row += 4) {
        float v = kb[(size_t)row * DDIM + lane];
        unsigned long long m = __ballot(v > 0.0f);
        if (lane == 0) ksig[row] = make_uint2((unsigned)m, (unsigned)(m >> 32));
    }
    __syncthreads();

    const float* qb = query + (size_t)b * LSEQ * DDIM;
    unsigned long long below = (1ull << lane) - 1ull;
    for (int t = 0; t < 16; ++t) {
        int qi = qblk * 64 + wave * 16 + t;
        float v = qb[(size_t)qi * DDIM + lane];
        unsigned long long qm = __ballot(v > 0.0f);
        unsigned q1 = (unsigned)qm, q2 = (unsigned)(qm >> 32);
        int* obase = out + ((size_t)b * LSEQ + qi) * KMAX;
        int cnt = 0;
#pragma unroll 8
        for (int c = 0; c < LSEQ / 64; ++c) {
            uint2 kv = ksig[c * 64 + lane];         // 2-way bank alias: free
            bool m = (kv.x == q1) || (kv.y == q2);
            unsigned long long mask = __ballot(m);
            if (m) {
                int pos = cnt + __popcll(mask & below);
                if (pos < KMAX) obase[pos] = c * 64 + lane;
            }
            cnt += __popcll(mask);
        }
        if (lane >= cnt) obase[lane] = -1;
    }
}

extern "C" void kernel_launch(void* const* d_in, const int* in_sizes, int n_in,
                              void* d_out, int out_size, void* d_ws, size_t ws_size,
                              hipStream_t stream) {
    const float* q = (const float*)d_in[0];
    const float* k = (const float*)d_in[1];
    // d_in[2] = head_idx, unused (inputs are already per-head)
    int* out = (int*)d_out;

    int total = in_sizes[0];             // B * L * D
    int B = total / (LSEQ * DDIM);       // = 4
    int nrows = B * LSEQ;                // key rows == queries == 8192

    size_t need = (size_t)nrows * 2 * sizeof(uint2);   // 128 KB
    if (ws_size >= need) {
        uint2* ksig = (uint2*)d_ws;
        uint2* qsig = ksig + nrows;
        int sig_threads = 2 * nrows * 64;            // one wave per row
        sig_kernel<<<(sig_threads + 255) / 256, 256, 0, stream>>>(
            q, k, ksig, qsig, nrows);
        int mt = nrows * 64;                         // one wave per query
        match_kernel<<<(mt + 255) / 256, 256, 0, stream>>>(qsig, ksig, out, nrows);
    } else {
        fused_kernel<<<B * (LSEQ / 64), 256, 0, stream>>>(q, k, out);
    }
}